// Round 1
// baseline (616.775 us; speedup 1.0000x reference)
//
#include <hip/hip_runtime.h>
#include <hip/hip_bf16.h>

#define NB 512
#define NT 256
#define NV 27
#define NE 64
#define NH 128

__device__ __forceinline__ float fast_tanh(float x) {
    // tanh(x) = 1 - 2/(e^{2x}+1); exact at both saturation ends.
    float e = __expf(2.0f * x);
    return 1.0f - 2.0f * __builtin_amdgcn_rcpf(e + 1.0f);
}

// embW[v][j] = b[j] + sum_e emb[v][e] * W[e][j]   (x_t @ W == embW[id_t])
__global__ void embw_kernel(const float* __restrict__ emb,
                            const float* __restrict__ W,
                            const float* __restrict__ bias,
                            float* __restrict__ out) {
    const int v = blockIdx.x;
    const int j = threadIdx.x;
    float acc = bias[j];
    #pragma unroll
    for (int e = 0; e < NE; ++e)
        acc = fmaf(emb[v * NE + e], W[e * NH + j], acc);
    out[v * NH + j] = acc;
}

__global__ __launch_bounds__(256, 1) void rnn_kernel(
    const int* __restrict__ enc_ids,
    const int* __restrict__ dec_ids,
    const float* __restrict__ U_enc,
    const float* __restrict__ U_dec,
    const float* __restrict__ embw,   // [2][NV][NH] (enc table, then dec table)
    const float* __restrict__ W_out,  // [NH][NV]
    const float* __restrict__ b_out,  // [NV]
    float* __restrict__ out)          // [NB][NT][NV]
{
    __shared__ float ring[8][2][NH];      // 8-step h ring, 2 batch rows
    __shared__ float Wt[NV][132];         // W_out^T, padded row stride
    __shared__ float embw_lds[2 * NV * NH];
    __shared__ int   ids[2][2][NT];
    __shared__ float bo[32];

    const int tid = threadIdx.x;
    const int b0  = blockIdx.x * 2;   // 2 batch rows per block
    const int r   = tid >> 7;         // 0/1: which row this thread updates
    const int j   = tid & 127;        // h column

    // ---- stage LDS ----
    for (int i = tid; i < 2 * NV * NH; i += 256) embw_lds[i] = embw[i];
    for (int i = tid; i < NV * NH; i += 256) {
        const int k = i & 127, v = i >> 7;
        Wt[v][k] = W_out[k * NV + v];
    }
    ids[0][0][tid] = enc_ids[(b0 + 0) * NT + tid];
    ids[0][1][tid] = enc_ids[(b0 + 1) * NT + tid];
    ids[1][0][tid] = dec_ids[(b0 + 0) * NT + tid];
    ids[1][1][tid] = dec_ids[(b0 + 1) * NT + tid];
    if (tid < NV) bo[tid] = b_out[tid];
    ring[7][r][j] = 0.0f;             // h0 = 0; step 0 reads slot 7

    // ---- U_enc column j in registers (fully unrolled so it stays in VGPRs) ----
    float u[NH];
    #pragma unroll
    for (int k = 0; k < NH; ++k) u[k] = U_enc[k * NH + j];

    __syncthreads();

    // ---- encoder: 256 steps ----
    #pragma unroll 1
    for (int s = 0; s < NT; ++s) {
        const int slot = s & 7, pslot = (s + 7) & 7;
        float acc = embw_lds[ids[0][r][s] * NH + j];
        const float* hp = ring[pslot][r];
        #pragma unroll
        for (int c = 0; c < 32; ++c) {
            const float4 hv = *(const float4*)(hp + 4 * c);  // broadcast ds_read_b128
            acc = fmaf(hv.x, u[4 * c + 0], acc);
            acc = fmaf(hv.y, u[4 * c + 1], acc);
            acc = fmaf(hv.z, u[4 * c + 2], acc);
            acc = fmaf(hv.w, u[4 * c + 3], acc);
        }
        ring[slot][r][j] = fast_tanh(acc);
        __syncthreads();   // write(s) visible before read(s+1); read/write slots differ
    }

    // ---- swap to U_dec (registers are private; no barrier needed) ----
    #pragma unroll
    for (int k = 0; k < NH; ++k) u[k] = U_dec[k * NH + j];

    // ---- decoder: 256 steps, logits flushed every 8 steps from the ring ----
    #pragma unroll 1
    for (int g = 0; g < NT / 8; ++g) {
        #pragma unroll 1
        for (int si = 0; si < 8; ++si) {
            const int t = g * 8 + si;                 // slot t&7 == si
            const int slot = t & 7, pslot = (t + 7) & 7;
            float acc = embw_lds[NV * NH + ids[1][r][t] * NH + j];
            const float* hp = ring[pslot][r];
            #pragma unroll
            for (int c = 0; c < 32; ++c) {
                const float4 hv = *(const float4*)(hp + 4 * c);
                acc = fmaf(hv.x, u[4 * c + 0], acc);
                acc = fmaf(hv.y, u[4 * c + 1], acc);
                acc = fmaf(hv.z, u[4 * c + 2], acc);
                acc = fmaf(hv.w, u[4 * c + 3], acc);
            }
            ring[slot][r][j] = fast_tanh(acc);
            __syncthreads();
        }
        // logits for t in [8g, 8g+8): 2 rows * 8 steps * 27 vocab = 432 dots
        for (int idx = tid; idx < 2 * 8 * NV; idx += 256) {
            const int v  = idx % NV;
            const int rt = idx / NV;          // 0..15
            const int rr = rt & 1;
            const int t  = g * 8 + (rt >> 1);
            const float* hp = ring[t & 7][rr];
            float acc = bo[v];
            #pragma unroll
            for (int c = 0; c < 32; ++c) {
                const float4 hv = *(const float4*)(hp + 4 * c);
                acc = fmaf(hv.x, Wt[v][4 * c + 0], acc);
                acc = fmaf(hv.y, Wt[v][4 * c + 1], acc);
                acc = fmaf(hv.z, Wt[v][4 * c + 2], acc);
                acc = fmaf(hv.w, Wt[v][4 * c + 3], acc);
            }
            out[((size_t)(b0 + rr) * NT + t) * NV + v] = acc;
        }
        __syncthreads();  // flush reads done before next group overwrites slots
    }
}

extern "C" void kernel_launch(void* const* d_in, const int* in_sizes, int n_in,
                              void* d_out, int out_size, void* d_ws, size_t ws_size,
                              hipStream_t stream) {
    const int*   enc_ids = (const int*)  d_in[0];
    const int*   dec_ids = (const int*)  d_in[1];
    const float* emb     = (const float*)d_in[2];
    const float* W_enc   = (const float*)d_in[3];
    const float* U_enc   = (const float*)d_in[4];
    const float* b_enc   = (const float*)d_in[5];
    const float* W_dec   = (const float*)d_in[6];
    const float* U_dec   = (const float*)d_in[7];
    const float* b_dec   = (const float*)d_in[8];
    const float* W_out   = (const float*)d_in[9];
    const float* b_out   = (const float*)d_in[10];
    float* outp = (float*)d_out;
    float* wsf  = (float*)d_ws;   // [2][NV][NH] = 27.6 KB

    embw_kernel<<<NV, NH, 0, stream>>>(emb, W_enc, b_enc, wsf);
    embw_kernel<<<NV, NH, 0, stream>>>(emb, W_dec, b_dec, wsf + NV * NH);
    rnn_kernel<<<NB / 2, 256, 0, stream>>>(enc_ids, dec_ids, U_enc, U_dec,
                                           wsf, W_out, b_out, outp);
}

// Round 2
// 333.810 us; speedup vs baseline: 1.8477x; 1.8477x over previous
//
#include <hip/hip_runtime.h>
#include <hip/hip_bf16.h>

#define NB 512
#define NT 256
#define NV 27
#define NE 64
#define NH 128

__device__ __forceinline__ float fast_tanh(float x) {
    // tanh(x) = 1 - 2/(e^{2x}+1); exact at both saturation ends.
    float e = __expf(2.0f * x);
    return 1.0f - 2.0f * __builtin_amdgcn_rcpf(e + 1.0f);
}

// sum with lane (lane ^ mask) via DPP quad_perm, full-rate VALU (no DS ops)
template<int CTRL>
__device__ __forceinline__ float dpp_xadd(float x) {
    int t = __builtin_amdgcn_mov_dpp(__float_as_int(x), CTRL, 0xF, 0xF, true);
    return x + __int_as_float(t);
}
// sum lane l with lane l^32 via v_permlane32_swap (gfx950), full-rate VALU
__device__ __forceinline__ float permlane32_sum(float x) {
    float a = x, b = x;
    asm("v_permlane32_swap_b32 %0, %1" : "+v"(a), "+v"(b));
    return a + b;
}
// full sum over the 8 split-k lanes (lane bits {0,1,5}); result in ALL lanes
__device__ __forceinline__ float red8(float x) {
    x = dpp_xadd<0xB1>(x);   // quad_perm [1,0,3,2]  : xor 1
    x = dpp_xadd<0x4E>(x);   // quad_perm [2,3,0,1]  : xor 2
    return permlane32_sum(x);// xor 32
}

// embW[tbl][v][j] = b[j] + sum_e emb[v][e] * W[e][j]   (x_t @ W == embW[id_t])
__global__ void embw_kernel(const float* __restrict__ emb,
                            const float* __restrict__ W_enc,
                            const float* __restrict__ b_enc,
                            const float* __restrict__ W_dec,
                            const float* __restrict__ b_dec,
                            float* __restrict__ out) {
    const int tbl = blockIdx.x / NV;
    const int v   = blockIdx.x % NV;
    const int j   = threadIdx.x;
    const float* W    = tbl ? W_dec : W_enc;
    const float* bias = tbl ? b_dec : b_enc;
    float acc = bias[j];
    #pragma unroll
    for (int e = 0; e < NE; ++e)
        acc = fmaf(emb[v * NE + e], W[e * NH + j], acc);
    out[tbl * NV * NH + v * NH + j] = acc;
}

// Ring layout: h chunk s (cols 16s..16s+15) lives at float offset 20*s within a
// slot (16 floats + 4 pad) -> the 8 split-k broadcast b128 reads hit 8 distinct
// bank-quads (5*s mod 8 is a permutation). Slot = 168 floats.
#define RING_W 168

__global__ __launch_bounds__(256, 2) void rnn_kernel(
    const int* __restrict__ enc_ids,
    const int* __restrict__ dec_ids,
    const float* __restrict__ U_enc,
    const float* __restrict__ U_dec,
    const float* __restrict__ embw,   // [2][NV][NH]
    const float* __restrict__ W_out,  // [NH][NV]
    const float* __restrict__ b_out,  // [NV]
    float* __restrict__ out)          // [NB][NT][NV]
{
    __shared__ __align__(16) float ring[2][RING_W];
    __shared__ __align__(16) float embw_lds[2 * NV * NH];
    __shared__ int ids_lds[2 * NT];

    const int tid = threadIdx.x;
    const int b   = blockIdx.x;                 // one batch row per block
    const int l   = tid & 63;                   // lane
    const int w   = tid >> 6;                   // wave 0..3
    // split-k index s on lane bits {0,1,5}; col-group on bits {2,3,4}
    const int s   = (l & 1) | (((l >> 1) & 1) << 1) | ((l >> 5) << 2);  // 0..7
    const int cg  = (l >> 2) & 7;                                       // 0..7
    const int j0  = 32 * w + 4 * cg;            // first of this thread's 4 cols

    // ---- stage LDS ----
    for (int i = tid; i < 2 * NV * NH / 4; i += 256)
        ((float4*)embw_lds)[i] = ((const float4*)embw)[i];
    ids_lds[tid]      = enc_ids[b * NT + tid];
    ids_lds[NT + tid] = dec_ids[b * NT + tid];
    if (tid < RING_W) ring[0][tid] = 0.0f;      // h0 = 0

    // ---- U_enc fragment: 4 cols x 16 k in registers ----
    float4 u4[16];
    #pragma unroll
    for (int kk = 0; kk < 16; ++kk)
        u4[kk] = *(const float4*)(U_enc + (16 * s + kk) * NH + j0);

    // write-lane info (lanes l<32 own col jw = 32w + l)
    const int jw    = 32 * w + (l & 31);
    const int woff  = 20 * (jw >> 4) + (jw & 15);  // swizzled float offset
    const bool wlane = (l < 32);

    __syncthreads();

    // =========================== encoder: 256 steps ===========================
    #pragma unroll 1
    for (int t = 0; t < NT; ++t) {
        const float4* hp4 = (const float4*)(&ring[t & 1][20 * s]);
        float4 a4 = {0.f, 0.f, 0.f, 0.f};
        #pragma unroll
        for (int m = 0; m < 4; ++m) {
            const float4 h4 = hp4[m];
            a4.x = fmaf(h4.x, u4[4*m+0].x, a4.x); a4.y = fmaf(h4.x, u4[4*m+0].y, a4.y);
            a4.z = fmaf(h4.x, u4[4*m+0].z, a4.z); a4.w = fmaf(h4.x, u4[4*m+0].w, a4.w);
            a4.x = fmaf(h4.y, u4[4*m+1].x, a4.x); a4.y = fmaf(h4.y, u4[4*m+1].y, a4.y);
            a4.z = fmaf(h4.y, u4[4*m+1].z, a4.z); a4.w = fmaf(h4.y, u4[4*m+1].w, a4.w);
            a4.x = fmaf(h4.z, u4[4*m+2].x, a4.x); a4.y = fmaf(h4.z, u4[4*m+2].y, a4.y);
            a4.z = fmaf(h4.z, u4[4*m+2].z, a4.z); a4.w = fmaf(h4.z, u4[4*m+2].w, a4.w);
            a4.x = fmaf(h4.w, u4[4*m+3].x, a4.x); a4.y = fmaf(h4.w, u4[4*m+3].y, a4.y);
            a4.z = fmaf(h4.w, u4[4*m+3].z, a4.z); a4.w = fmaf(h4.w, u4[4*m+3].w, a4.w);
        }
        a4.x = red8(a4.x); a4.y = red8(a4.y); a4.z = red8(a4.z); a4.w = red8(a4.w);
        // select this lane's column value (static cndmask chain, no local mem)
        float x0 = (l & 1) ? a4.y : a4.x;
        float x1 = (l & 1) ? a4.w : a4.z;
        float xs = (l & 2) ? x1 : x0;
        const int id = ids_lds[t];
        xs += embw_lds[id * NH + jw];
        const float h = fast_tanh(xs);
        if (wlane) ring[(t + 1) & 1][woff] = h;
        __syncthreads();
    }

    // ======================= switch to decoder weights =======================
    #pragma unroll
    for (int kk = 0; kk < 16; ++kk)
        u4[kk] = *(const float4*)(U_dec + (16 * s + kk) * NH + j0);
    // logits: this thread also owns W_out[k-chunk s][v = 8w+cg] in registers
    const int  v   = 8 * w + cg;                 // 0..31
    const bool vok = (v < NV);
    float wtc[16];
    #pragma unroll
    for (int kk = 0; kk < 16; ++kk)
        wtc[kk] = vok ? W_out[(16 * s + kk) * NV + v] : 0.0f;
    const float bov = vok ? b_out[v] : 0.0f;
    const bool lstore = vok && ((l & 3) == 0) && (l < 32);

    // ================= decoder: 256 steps + 1 logits-tail iter ================
    // iter t: recurrence consumes dec input t (t<256); logits of state read this
    // iter (= dec_hs[t-1]) are emitted for t>=1.
    #pragma unroll 1
    for (int t = 0; t <= NT; ++t) {
        const float4* hp4 = (const float4*)(&ring[t & 1][20 * s]);
        float4 h4s[4];
        #pragma unroll
        for (int m = 0; m < 4; ++m) h4s[m] = hp4[m];

        if (t >= 1) {   // logits for dec step t-1
            float lacc = 0.f;
            #pragma unroll
            for (int m = 0; m < 4; ++m) {
                lacc = fmaf(h4s[m].x, wtc[4*m+0], lacc);
                lacc = fmaf(h4s[m].y, wtc[4*m+1], lacc);
                lacc = fmaf(h4s[m].z, wtc[4*m+2], lacc);
                lacc = fmaf(h4s[m].w, wtc[4*m+3], lacc);
            }
            lacc = red8(lacc);
            if (lstore)
                out[((size_t)b * NT + (t - 1)) * NV + v] = lacc + bov;
        }

        if (t < NT) {
            float4 a4 = {0.f, 0.f, 0.f, 0.f};
            #pragma unroll
            for (int m = 0; m < 4; ++m) {
                const float4 h4 = h4s[m];
                a4.x = fmaf(h4.x, u4[4*m+0].x, a4.x); a4.y = fmaf(h4.x, u4[4*m+0].y, a4.y);
                a4.z = fmaf(h4.x, u4[4*m+0].z, a4.z); a4.w = fmaf(h4.x, u4[4*m+0].w, a4.w);
                a4.x = fmaf(h4.y, u4[4*m+1].x, a4.x); a4.y = fmaf(h4.y, u4[4*m+1].y, a4.y);
                a4.z = fmaf(h4.y, u4[4*m+1].z, a4.z); a4.w = fmaf(h4.y, u4[4*m+1].w, a4.w);
                a4.x = fmaf(h4.z, u4[4*m+2].x, a4.x); a4.y = fmaf(h4.z, u4[4*m+2].y, a4.y);
                a4.z = fmaf(h4.z, u4[4*m+2].z, a4.z); a4.w = fmaf(h4.z, u4[4*m+2].w, a4.w);
                a4.x = fmaf(h4.w, u4[4*m+3].x, a4.x); a4.y = fmaf(h4.w, u4[4*m+3].y, a4.y);
                a4.z = fmaf(h4.w, u4[4*m+3].z, a4.z); a4.w = fmaf(h4.w, u4[4*m+3].w, a4.w);
            }
            a4.x = red8(a4.x); a4.y = red8(a4.y); a4.z = red8(a4.z); a4.w = red8(a4.w);
            float x0 = (l & 1) ? a4.y : a4.x;
            float x1 = (l & 1) ? a4.w : a4.z;
            float xs = (l & 2) ? x1 : x0;
            const int id = ids_lds[NT + t];
            xs += embw_lds[NV * NH + id * NH + jw];
            const float h = fast_tanh(xs);
            if (wlane) ring[(t + 1) & 1][woff] = h;
            __syncthreads();
        }
    }
}

extern "C" void kernel_launch(void* const* d_in, const int* in_sizes, int n_in,
                              void* d_out, int out_size, void* d_ws, size_t ws_size,
                              hipStream_t stream) {
    const int*   enc_ids = (const int*)  d_in[0];
    const int*   dec_ids = (const int*)  d_in[1];
    const float* emb     = (const float*)d_in[2];
    const float* W_enc   = (const float*)d_in[3];
    const float* U_enc   = (const float*)d_in[4];
    const float* b_enc   = (const float*)d_in[5];
    const float* W_dec   = (const float*)d_in[6];
    const float* U_dec   = (const float*)d_in[7];
    const float* b_dec   = (const float*)d_in[8];
    const float* W_out   = (const float*)d_in[9];
    const float* b_out   = (const float*)d_in[10];
    float* outp = (float*)d_out;
    float* wsf  = (float*)d_ws;   // [2][NV][NH] = 27.6 KB

    embw_kernel<<<2 * NV, NH, 0, stream>>>(emb, W_enc, b_enc, W_dec, b_dec, wsf);
    rnn_kernel<<<NB, 256, 0, stream>>>(enc_ids, dec_ids, U_enc, U_dec,
                                       wsf, W_out, b_out, outp);
}

// Round 5
// 331.214 us; speedup vs baseline: 1.8622x; 1.0078x over previous
//
#include <hip/hip_runtime.h>
#include <hip/hip_bf16.h>

#define NB 512
#define NT 256
#define NV 27
#define NE 64
#define NH 128

__device__ __forceinline__ float fast_tanh(float x) {
    // tanh(x) = 1 - 2/(e^{2x}+1); exact at both saturation ends.
    float e = __expf(2.0f * x);
    return 1.0f - 2.0f * __builtin_amdgcn_rcpf(e + 1.0f);
}

// x + x(lane^mask) via DPP quad_perm, full-rate VALU (no DS ops)
template<int CTRL>
__device__ __forceinline__ float dpp_xadd(float x) {
    int t = __builtin_amdgcn_mov_dpp(__float_as_int(x), CTRL, 0xF, 0xF, true);
    return x + __int_as_float(t);
}
// x + x(lane^32) via v_permlane32_swap (gfx950).
// REGISTER-AIRTIGHT: duplicate x inside the asm into two distinct early-clobber
// outputs. The old form (float a=x,b=x; asm("+v","+v")) let the allocator
// coalesce same-valued a,b into ONE register -> "swap v5,v5" = halves-swap in
// place -> a+b = 2*x[l^32] (wrong). That was the r3/r4 silent-corruption bug.
__device__ __forceinline__ float permlane32_sum(float x) {
    float a, b;
    asm("v_mov_b32 %0, %2\n\t"
        "v_mov_b32 %1, %2\n\t"
        "v_permlane32_swap_b32 %0, %1"
        : "=&v"(a), "=&v"(b)
        : "v"(x));
    return a + b;
}
// all-reduce over the 8 split-k lanes (lane bits {0,1,5}); result in ALL lanes
__device__ __forceinline__ float red8(float x) {
    x = dpp_xadd<0xB1>(x);   // xor 1
    x = dpp_xadd<0x4E>(x);   // xor 2
    return permlane32_sum(x);// xor 32
}

// embW[v][j] = b[j] + sum_e emb[v][e] * W[e][j]   (x_t @ W == embW[id_t])
__global__ void embw_kernel(const float* __restrict__ emb,
                            const float* __restrict__ W,
                            const float* __restrict__ bias,
                            float* __restrict__ out) {
    const int v = blockIdx.x;
    const int j = threadIdx.x;
    float acc = bias[j];
    #pragma unroll
    for (int e = 0; e < NE; ++e)
        acc = fmaf(emb[v * NE + e], W[e * NH + j], acc);
    out[v * NH + j] = acc;
}

// Ring layout: h chunk s (cols 16s..16s+15) at float offset 20*s (16 + 4 pad)
// -> the 8 split-k broadcast b128 reads cover all 32 banks exactly once.
#define RING_W 168

// 4-col MAC of one h scalar against one U row-fragment
#define MAC4(A, HS, U) \
    A.x = fmaf((HS), (U).x, A.x); A.y = fmaf((HS), (U).y, A.y); \
    A.z = fmaf((HS), (U).z, A.z); A.w = fmaf((HS), (U).w, A.w);

// full 16-k MAC over named u registers
#define DOT16(A, H0, H1, H2, H3) \
    MAC4(A, H0.x, u0)  MAC4(A, H0.y, u1)  MAC4(A, H0.z, u2)  MAC4(A, H0.w, u3)  \
    MAC4(A, H1.x, u4)  MAC4(A, H1.y, u5)  MAC4(A, H1.z, u6)  MAC4(A, H1.w, u7)  \
    MAC4(A, H2.x, u8)  MAC4(A, H2.y, u9)  MAC4(A, H2.z, u10) MAC4(A, H2.w, u11) \
    MAC4(A, H3.x, u12) MAC4(A, H3.y, u13) MAC4(A, H3.z, u14) MAC4(A, H3.w, u15)

// reload all 16 named u fragments from matrix P (rows 16s..16s+15, cols j0..j0+3)
#define LDU(P) \
    u0  = *(const float4*)((P) + (16 * s +  0) * NH + j0); \
    u1  = *(const float4*)((P) + (16 * s +  1) * NH + j0); \
    u2  = *(const float4*)((P) + (16 * s +  2) * NH + j0); \
    u3  = *(const float4*)((P) + (16 * s +  3) * NH + j0); \
    u4  = *(const float4*)((P) + (16 * s +  4) * NH + j0); \
    u5  = *(const float4*)((P) + (16 * s +  5) * NH + j0); \
    u6  = *(const float4*)((P) + (16 * s +  6) * NH + j0); \
    u7  = *(const float4*)((P) + (16 * s +  7) * NH + j0); \
    u8  = *(const float4*)((P) + (16 * s +  8) * NH + j0); \
    u9  = *(const float4*)((P) + (16 * s +  9) * NH + j0); \
    u10 = *(const float4*)((P) + (16 * s + 10) * NH + j0); \
    u11 = *(const float4*)((P) + (16 * s + 11) * NH + j0); \
    u12 = *(const float4*)((P) + (16 * s + 12) * NH + j0); \
    u13 = *(const float4*)((P) + (16 * s + 13) * NH + j0); \
    u14 = *(const float4*)((P) + (16 * s + 14) * NH + j0); \
    u15 = *(const float4*)((P) + (16 * s + 15) * NH + j0);

__global__ __attribute__((amdgpu_waves_per_eu(2, 2))) __launch_bounds__(256)
void rnn_kernel(
    const int* __restrict__ enc_ids,
    const int* __restrict__ dec_ids,
    const float* __restrict__ U_enc,
    const float* __restrict__ U_dec,
    const float* __restrict__ embw,   // [2][NV][NH]
    const float* __restrict__ W_out,  // [NH][NV]
    const float* __restrict__ b_out,  // [NV]
    float* __restrict__ out)          // [NB][NT][NV]
{
    __shared__ __align__(16) float ring[2][RING_W];
    __shared__ __align__(16) float embw_lds[2 * NV * NH];
    __shared__ int ids_lds[2 * NT];

    const int tid = threadIdx.x;
    const int b   = blockIdx.x;                 // one batch row per block
    const int l   = tid & 63;                   // lane
    const int w   = tid >> 6;                   // wave 0..3
    const int s   = (l & 3) | ((l >> 5) << 2);  // split-k chunk 0..7 (bits 0,1,5)
    const int cg  = (l >> 2) & 7;               // col-group 0..7 (bits 2,3,4)
    const int j0  = 32 * w + 4 * cg;

    // ---- stage LDS ----
    for (int i = tid; i < 2 * NV * NH / 4; i += 256)
        ((float4*)embw_lds)[i] = ((const float4*)embw)[i];
    ids_lds[tid]      = enc_ids[b * NT + tid];
    ids_lds[NT + tid] = dec_ids[b * NT + tid];
    if (tid < RING_W) ring[0][tid] = 0.0f;      // h0 = 0

    // ---- U_enc fragment: 4 cols x 16 k in NAMED registers (SROA-proof) ----
    float4 u0, u1, u2, u3, u4, u5, u6, u7, u8, u9, u10, u11, u12, u13, u14, u15;
    LDU(U_enc)

    // write-lane info (lanes l<32 own col jw = 32w + l)
    const int jw    = 32 * w + (l & 31);
    const int woff  = 20 * (jw >> 4) + (jw & 15);  // swizzled float offset
    const bool wlane = (l < 32);

    __syncthreads();

    // =========================== encoder: 256 steps ===========================
    float xen = embw_lds[(ids_lds[0] << 7) + jw];
    #pragma unroll 1
    for (int t = 0; t < NT; ++t) {
        const float4* hp4 = (const float4*)(&ring[t & 1][20 * s]);
        const float4 h0 = hp4[0], h1 = hp4[1], h2 = hp4[2], h3 = hp4[3];
        const float xe = xen;
        { // prefetch next step's input (post-barrier-constant LDS; hazard-free)
            const int id2 = ids_lds[(t + 1) & (NT - 1)];
            xen = embw_lds[(id2 << 7) + jw];
        }
        float4 a4 = {0.f, 0.f, 0.f, 0.f};
        DOT16(a4, h0, h1, h2, h3)
        a4.x = red8(a4.x); a4.y = red8(a4.y); a4.z = red8(a4.z); a4.w = red8(a4.w);
        // select this lane's column value (col jw = j0 + 2*b1 + b0)
        float x0 = (l & 1) ? a4.y : a4.x;
        float x1 = (l & 1) ? a4.w : a4.z;
        float xs = (l & 2) ? x1 : x0;
        const float h = fast_tanh(xs + xe);
        if (wlane) ring[(t + 1) & 1][woff] = h;
        __syncthreads();
    }

    // ======================= switch to decoder weights =======================
    LDU(U_dec)
    // logits: this thread also owns W_out[k-chunk s][vv = 8w+cg] in registers
    const int  vv  = 8 * w + cg;                 // 0..31
    const bool vok = (vv < NV);
    float wt0, wt1, wt2, wt3, wt4, wt5, wt6, wt7;
    float wt8, wt9, wt10, wt11, wt12, wt13, wt14, wt15;
    {
        const float* Wp = W_out + 16 * s * NV + (vok ? vv : 0);
        wt0  = vok ? Wp[ 0 * NV] : 0.0f;  wt1  = vok ? Wp[ 1 * NV] : 0.0f;
        wt2  = vok ? Wp[ 2 * NV] : 0.0f;  wt3  = vok ? Wp[ 3 * NV] : 0.0f;
        wt4  = vok ? Wp[ 4 * NV] : 0.0f;  wt5  = vok ? Wp[ 5 * NV] : 0.0f;
        wt6  = vok ? Wp[ 6 * NV] : 0.0f;  wt7  = vok ? Wp[ 7 * NV] : 0.0f;
        wt8  = vok ? Wp[ 8 * NV] : 0.0f;  wt9  = vok ? Wp[ 9 * NV] : 0.0f;
        wt10 = vok ? Wp[10 * NV] : 0.0f;  wt11 = vok ? Wp[11 * NV] : 0.0f;
        wt12 = vok ? Wp[12 * NV] : 0.0f;  wt13 = vok ? Wp[13 * NV] : 0.0f;
        wt14 = vok ? Wp[14 * NV] : 0.0f;  wt15 = vok ? Wp[15 * NV] : 0.0f;
    }
    const float bov = vok ? b_out[vv] : 0.0f;
    const bool lstore = vok && ((l & 3) == 0) && (l < 32);

    // ================= decoder: 256 steps + 1 logits-tail iter ================
    // iter t: recurrence consumes dec input t (t<256); logits of state read this
    // iter (= dec_hs[t-1]) are emitted for t>=1.
    float xdn = embw_lds[NV * NH + (ids_lds[NT] << 7) + jw];
    #pragma unroll 1
    for (int t = 0; t <= NT; ++t) {
        const float4* hp4 = (const float4*)(&ring[t & 1][20 * s]);
        const float4 h0 = hp4[0], h1 = hp4[1], h2 = hp4[2], h3 = hp4[3];
        const float xe = xdn;
        {
            const int id2 = ids_lds[NT + ((t + 1) & (NT - 1))];
            xdn = embw_lds[NV * NH + (id2 << 7) + jw];
        }

        if (t >= 1) {   // logits for dec step t-1 (state read this iter)
            float lacc;
            lacc = h0.x * wt0;
            lacc = fmaf(h0.y, wt1,  lacc); lacc = fmaf(h0.z, wt2,  lacc);
            lacc = fmaf(h0.w, wt3,  lacc); lacc = fmaf(h1.x, wt4,  lacc);
            lacc = fmaf(h1.y, wt5,  lacc); lacc = fmaf(h1.z, wt6,  lacc);
            lacc = fmaf(h1.w, wt7,  lacc); lacc = fmaf(h2.x, wt8,  lacc);
            lacc = fmaf(h2.y, wt9,  lacc); lacc = fmaf(h2.z, wt10, lacc);
            lacc = fmaf(h2.w, wt11, lacc); lacc = fmaf(h3.x, wt12, lacc);
            lacc = fmaf(h3.y, wt13, lacc); lacc = fmaf(h3.z, wt14, lacc);
            lacc = fmaf(h3.w, wt15, lacc);
            lacc = red8(lacc);
            if (lstore)
                out[((size_t)b * NT + (t - 1)) * NV + vv] = lacc + bov;
        }

        if (t < NT) {
            float4 a4 = {0.f, 0.f, 0.f, 0.f};
            DOT16(a4, h0, h1, h2, h3)
            a4.x = red8(a4.x); a4.y = red8(a4.y); a4.z = red8(a4.z); a4.w = red8(a4.w);
            float x0 = (l & 1) ? a4.y : a4.x;
            float x1 = (l & 1) ? a4.w : a4.z;
            float xs = (l & 2) ? x1 : x0;
            const float h = fast_tanh(xs + xe);
            if (wlane) ring[(t + 1) & 1][woff] = h;
            __syncthreads();
        }
    }
}

extern "C" void kernel_launch(void* const* d_in, const int* in_sizes, int n_in,
                              void* d_out, int out_size, void* d_ws, size_t ws_size,
                              hipStream_t stream) {
    const int*   enc_ids = (const int*)  d_in[0];
    const int*   dec_ids = (const int*)  d_in[1];
    const float* emb     = (const float*)d_in[2];
    const float* W_enc   = (const float*)d_in[3];
    const float* U_enc   = (const float*)d_in[4];
    const float* b_enc   = (const float*)d_in[5];
    const float* W_dec   = (const float*)d_in[6];
    const float* U_dec   = (const float*)d_in[7];
    const float* b_dec   = (const float*)d_in[8];
    const float* W_out   = (const float*)d_in[9];
    const float* b_out   = (const float*)d_in[10];
    float* outp = (float*)d_out;
    float* wsf  = (float*)d_ws;   // [2][NV][NH] = 27.6 KB

    embw_kernel<<<NV, NH, 0, stream>>>(emb, W_enc, b_enc, wsf);
    embw_kernel<<<NV, NH, 0, stream>>>(emb, W_dec, b_dec, wsf + NV * NH);
    rnn_kernel<<<NB, 256, 0, stream>>>(enc_ids, dec_ids, U_enc, U_dec,
                                       wsf, W_out, b_out, outp);
}

// Round 6
// 262.654 us; speedup vs baseline: 2.3482x; 1.2610x over previous
//
#include <hip/hip_runtime.h>
#include <hip/hip_bf16.h>

#define NB 512
#define NT 256
#define NV 27
#define NE 64
#define NH 128

typedef float v2f __attribute__((ext_vector_type(2)));

__device__ __forceinline__ v2f mk2(float a, float b) { v2f r; r.x = a; r.y = b; return r; }
__device__ __forceinline__ v2f pkfma(v2f a, v2f b, v2f c) {
    return __builtin_elementwise_fma(a, b, c);   // -> v_pk_fma_f32
}

__device__ __forceinline__ float fast_tanh(float x) {
    // tanh(x) = 1 - 2/(2^(2x*log2e)+1); exact at both saturation ends (inf/0).
    float e = __builtin_amdgcn_exp2f(x * 2.885390081777927f);
    return fmaf(-2.0f, __builtin_amdgcn_rcpf(e + 1.0f), 1.0f);
}

// x + x(lane^mask) via DPP quad_perm, full-rate VALU (no DS ops)
template<int CTRL>
__device__ __forceinline__ float dpp_xadd(float x) {
    int t = __builtin_amdgcn_mov_dpp(__float_as_int(x), CTRL, 0xF, 0xF, true);
    return x + __int_as_float(t);
}
// x + x(lane^32) via v_permlane32_swap (gfx950). REGISTER-AIRTIGHT form:
// duplicate inside the asm into two distinct early-clobber outputs (the "+v","+v"
// same-value form let the allocator coalesce them -> in-place half-swap bug).
__device__ __forceinline__ float permlane32_sum(float x) {
    float a, b;
    asm("v_mov_b32 %0, %2\n\t"
        "v_mov_b32 %1, %2\n\t"
        "v_permlane32_swap_b32 %0, %1"
        : "=&v"(a), "=&v"(b) : "v"(x));
    return a + b;
}
// all-reduce over the 8 split-k lanes (lane bits {0,1,5}); result in ALL lanes
__device__ __forceinline__ float red8(float x) {
    x = dpp_xadd<0xB1>(x);    // xor 1
    x = dpp_xadd<0x4E>(x);    // xor 2
    return permlane32_sum(x); // xor 32
}
// reduce-SCATTER over lane bits {0,1,5}: inputs = partials for cols j0..j0+3 of
// this lane's k-chunk; output = FULL sum for col jc = j0 + 2*b0 + b1.
__device__ __forceinline__ float rs8(float ax, float ay, float az, float aw,
                                     bool b0, bool b1) {
    float A = dpp_xadd<0xB1>(ax);     // col j0+0 over b0-pairs
    float B = dpp_xadd<0xB1>(ay);
    float C = dpp_xadd<0xB1>(az);
    float D = dpp_xadd<0xB1>(aw);
    float v0 = b0 ? C : A;            // col j0 + 2*b0
    float v1 = b0 ? D : B;            // col j0 + 2*b0 + 1
    v0 = dpp_xadd<0x4E>(v0);          // over b1-pairs
    v1 = dpp_xadd<0x4E>(v1);
    float v = b1 ? v1 : v0;           // col j0 + 2*b0 + b1
    return permlane32_sum(v);         // over b5-pairs
}

// embW[v][j] = b[j] + sum_e emb[v][e] * W[e][j]   (x_t @ W == embW[id_t])
__global__ void embw_kernel(const float* __restrict__ emb,
                            const float* __restrict__ W,
                            const float* __restrict__ bias,
                            float* __restrict__ out) {
    const int v = blockIdx.x;
    const int j = threadIdx.x;
    float acc = bias[j];
    #pragma unroll
    for (int e = 0; e < NE; ++e)
        acc = fmaf(emb[v * NE + e], W[e * NH + j], acc);
    out[v * NH + j] = acc;
}

// Ring layout: h chunk s (cols 16s..16s+15) at float offset 20*s (16 + 4 pad)
// -> the 8 split-k broadcast b128 reads cover all 32 banks exactly once.
#define RING_W 168

// ---- U fragment as k-PAIR float2s, one set of 8 per column (transposed) ----
#define LDC(P, C, OFF) \
    C##0 = mk2((P)[(16*s+ 0)*NH + j0+(OFF)], (P)[(16*s+ 1)*NH + j0+(OFF)]); \
    C##1 = mk2((P)[(16*s+ 2)*NH + j0+(OFF)], (P)[(16*s+ 3)*NH + j0+(OFF)]); \
    C##2 = mk2((P)[(16*s+ 4)*NH + j0+(OFF)], (P)[(16*s+ 5)*NH + j0+(OFF)]); \
    C##3 = mk2((P)[(16*s+ 6)*NH + j0+(OFF)], (P)[(16*s+ 7)*NH + j0+(OFF)]); \
    C##4 = mk2((P)[(16*s+ 8)*NH + j0+(OFF)], (P)[(16*s+ 9)*NH + j0+(OFF)]); \
    C##5 = mk2((P)[(16*s+10)*NH + j0+(OFF)], (P)[(16*s+11)*NH + j0+(OFF)]); \
    C##6 = mk2((P)[(16*s+12)*NH + j0+(OFF)], (P)[(16*s+13)*NH + j0+(OFF)]); \
    C##7 = mk2((P)[(16*s+14)*NH + j0+(OFF)], (P)[(16*s+15)*NH + j0+(OFF)]);
#define LDALL(P) LDC(P,ua,0) LDC(P,ub,1) LDC(P,uc,2) LDC(P,ud,3)

// Pin fragments to arch VGPRs (not AGPRs) at each use site.
#define PIN8(C) asm("" : "+v"(C##0),"+v"(C##1),"+v"(C##2),"+v"(C##3), \
                        "+v"(C##4),"+v"(C##5),"+v"(C##6),"+v"(C##7));
#define PINU PIN8(ua) PIN8(ub) PIN8(uc) PIN8(ud)

// per-column dot over this lane's 16 k: 8 pk-FMA in 2 chains + merge
#define DOTC(RES, C) { \
    v2f q1 = p0 * C##0; \
    q1 = pkfma(p1, C##1, q1); q1 = pkfma(p2, C##2, q1); q1 = pkfma(p3, C##3, q1); \
    v2f q2 = p4 * C##4; \
    q2 = pkfma(p5, C##5, q2); q2 = pkfma(p6, C##6, q2); q2 = pkfma(p7, C##7, q2); \
    v2f qq = q1 + q2; RES = qq.x + qq.y; }

// load this lane's h chunk (16 k) from ring slot RD as 8 even-aligned pairs
#define HLOAD(RD) \
    const float4* hp4 = (const float4*)(&ring[RD][rdo]); \
    const float4 h0 = hp4[0], h1 = hp4[1], h2 = hp4[2], h3 = hp4[3]; \
    const v2f p0 = mk2(h0.x,h0.y), p1 = mk2(h0.z,h0.w), \
              p2 = mk2(h1.x,h1.y), p3 = mk2(h1.z,h1.w), \
              p4 = mk2(h2.x,h2.y), p5 = mk2(h2.z,h2.w), \
              p6 = mk2(h3.x,h3.y), p7 = mk2(h3.z,h3.w);

#define RECUR(WR, XE) \
    float cx, cy, cz, cw; \
    DOTC(cx, ua) DOTC(cy, ub) DOTC(cz, uc) DOTC(cw, ud) \
    const float xs = rs8(cx, cy, cz, cw, b0, b1); \
    const float h = fast_tanh(xs + (XE)); \
    if (wlane) ring[WR][woff] = h; \
    __syncthreads();

#define ESTEP(RD, WR, T) { \
    PINU \
    HLOAD(RD) \
    const float xe = xen; \
    { const int id2 = ids_lds[((T) + 1) & (NT - 1)]; \
      xen = embw_lds[(id2 << 7) + jc]; } \
    RECUR(WR, xe) }

#define LOGITS(T) { \
    v2f L1 = p0 * wp0; \
    L1 = pkfma(p1, wp1, L1); L1 = pkfma(p2, wp2, L1); L1 = pkfma(p3, wp3, L1); \
    v2f L2 = p4 * wp4; \
    L2 = pkfma(p5, wp5, L2); L2 = pkfma(p6, wp6, L2); L2 = pkfma(p7, wp7, L2); \
    v2f LL = L1 + L2; \
    const float lacc = red8(LL.x + LL.y); \
    if (lstore) out[((size_t)b * NT + ((T) - 1)) * NV + vv] = lacc + bov; }

#define DSTEP(RD, WR, T) { \
    PINU PIN8(wp) \
    HLOAD(RD) \
    const float xe = xdn; \
    { const int id2 = ids_lds[NT + (((T) + 1) & (NT - 1))]; \
      xdn = embw_lds[NV * NH + (id2 << 7) + jc]; } \
    LOGITS(T) \
    RECUR(WR, xe) }

__global__ __attribute__((amdgpu_waves_per_eu(2, 2))) __launch_bounds__(256)
void rnn_kernel(
    const int* __restrict__ enc_ids,
    const int* __restrict__ dec_ids,
    const float* __restrict__ U_enc,
    const float* __restrict__ U_dec,
    const float* __restrict__ embw,   // [2][NV][NH]
    const float* __restrict__ W_out,  // [NH][NV]
    const float* __restrict__ b_out,  // [NV]
    float* __restrict__ out)          // [NB][NT][NV]
{
    __shared__ __align__(16) float ring[2][RING_W];
    __shared__ __align__(16) float embw_lds[2 * NV * NH];
    __shared__ int ids_lds[2 * NT];

    const int tid = threadIdx.x;
    const int b   = blockIdx.x;                 // one batch row per block
    const int l   = tid & 63;                   // lane
    const int w   = tid >> 6;                   // wave 0..3
    const int s   = (l & 3) | ((l >> 5) << 2);  // split-k chunk (lane bits 0,1,5)
    const int cg  = (l >> 2) & 7;               // col-group (lane bits 2,3,4)
    const int j0  = 32 * w + 4 * cg;
    const bool b0 = (l & 1) != 0;
    const bool b1 = (l & 2) != 0;
    const int jc  = j0 + 2 * (int)b0 + (int)b1; // this lane's output column
    const int woff = 20 * (jc >> 4) + (jc & 15);
    const int rdo  = 20 * s;
    const bool wlane = (l < 32);                // b5-duplicates don't write

    // ---- stage LDS ----
    for (int i = tid; i < 2 * NV * NH / 4; i += 256)
        ((float4*)embw_lds)[i] = ((const float4*)embw)[i];
    ids_lds[tid]      = enc_ids[b * NT + tid];
    ids_lds[NT + tid] = dec_ids[b * NT + tid];
    if (tid < RING_W) ring[0][tid] = 0.0f;      // h0 = 0

    // ---- U_enc fragment: 4 cols x 8 k-pairs, named v2f registers ----
    v2f ua0, ua1, ua2, ua3, ua4, ua5, ua6, ua7;
    v2f ub0, ub1, ub2, ub3, ub4, ub5, ub6, ub7;
    v2f uc0, uc1, uc2, uc3, uc4, uc5, uc6, uc7;
    v2f ud0, ud1, ud2, ud3, ud4, ud5, ud6, ud7;
    LDALL(U_enc)

    __syncthreads();

    // =========================== encoder: 256 steps ===========================
    float xen = embw_lds[(ids_lds[0] << 7) + jc];
    #pragma unroll 1
    for (int t = 0; t < NT; t += 2) {
        ESTEP(0, 1, t)
        ESTEP(1, 0, t + 1)
    }

    // ======================= switch to decoder weights =======================
    LDALL(U_dec)
    const int  vv  = 8 * w + cg;                // 0..31
    const bool vok = (vv < NV);
    v2f wp0, wp1, wp2, wp3, wp4, wp5, wp6, wp7;
    {
        const float* Wp = W_out + 16 * s * NV + (vok ? vv : 0);
        wp0 = mk2(Wp[ 0*NV], Wp[ 1*NV]);  wp1 = mk2(Wp[ 2*NV], Wp[ 3*NV]);
        wp2 = mk2(Wp[ 4*NV], Wp[ 5*NV]);  wp3 = mk2(Wp[ 6*NV], Wp[ 7*NV]);
        wp4 = mk2(Wp[ 8*NV], Wp[ 9*NV]);  wp5 = mk2(Wp[10*NV], Wp[11*NV]);
        wp6 = mk2(Wp[12*NV], Wp[13*NV]);  wp7 = mk2(Wp[14*NV], Wp[15*NV]);
    }
    const float bov = vok ? b_out[vok ? vv : 0] : 0.0f;
    const bool lstore = vok && ((l & 3) == 0) && (l < 32);

    // ================= decoder: 256 steps + logits tail =================
    // iter t: recurrence consumes dec input t; logits of the state READ this
    // iter (= dec_hs[t-1]) are emitted for t>=1; tail iter emits dec_hs[255].
    float xdn = embw_lds[NV * NH + (ids_lds[NT] << 7) + jc];
    {   // t = 0: recurrence only (state read is the encoder final state)
        PINU
        HLOAD(0)
        const float xe = xdn;
        { const int id2 = ids_lds[NT + 1];
          xdn = embw_lds[NV * NH + (id2 << 7) + jc]; }
        RECUR(1, xe)
    }
    #pragma unroll 1
    for (int t = 1; t < NT - 1; t += 2) {
        DSTEP(1, 0, t)
        DSTEP(0, 1, t + 1)
    }
    DSTEP(1, 0, NT - 1)
    {   // tail: logits for dec step NT-1 from ring[0]
        PIN8(wp)
        HLOAD(0)
        LOGITS(NT)
    }
}

extern "C" void kernel_launch(void* const* d_in, const int* in_sizes, int n_in,
                              void* d_out, int out_size, void* d_ws, size_t ws_size,
                              hipStream_t stream) {
    const int*   enc_ids = (const int*)  d_in[0];
    const int*   dec_ids = (const int*)  d_in[1];
    const float* emb     = (const float*)d_in[2];
    const float* W_enc   = (const float*)d_in[3];
    const float* U_enc   = (const float*)d_in[4];
    const float* b_enc   = (const float*)d_in[5];
    const float* W_dec   = (const float*)d_in[6];
    const float* U_dec   = (const float*)d_in[7];
    const float* b_dec   = (const float*)d_in[8];
    const float* W_out   = (const float*)d_in[9];
    const float* b_out   = (const float*)d_in[10];
    float* outp = (float*)d_out;
    float* wsf  = (float*)d_ws;   // [2][NV][NH] = 27.6 KB

    embw_kernel<<<NV, NH, 0, stream>>>(emb, W_enc, b_enc, wsf);
    embw_kernel<<<NV, NH, 0, stream>>>(emb, W_dec, b_dec, wsf + NV * NH);
    rnn_kernel<<<NB, 256, 0, stream>>>(enc_ids, dec_ids, U_enc, U_dec,
                                       wsf, W_out, b_out, outp);
}